// Round 17
// baseline (212.272 us; speedup 1.0000x reference)
//
#include <hip/hip_runtime.h>

// GraphSAGE (mean) x3 + per-graph mean pool, MI355X.
// R17: wave-per-node gather. Old mapping (8 thr/node, 8 nodes/wave) paid
// E[max deg of 8]/E[deg] ~ 1.5x divergence tax per wave. New: one wave per
// node, lane=(eslot,dchunk); eslot e handles edges j==e (mod 8) -> uniform
// ceil(deg/8) iterations; 3-step shfl_xor reduce; eslot0 writes 128B row.
// R16's neutral fusions kept (prescan+toff last-block; prep=pack_B+cast).
// (R16's "regression" was clock drift: fillBuffer 6.4 vs 6.9 TB/s.)

#define DD 64
#define NBA 128    // blocks in count/scatter passes (= 2 x wave width)
#define CAP 4096   // per-bucket LDS sort capacity (avg bucket ~2560 edges)

typedef __attribute__((ext_vector_type(8))) short short8;   // 8 bf16 (4 VGPRs)
typedef __attribute__((ext_vector_type(4))) float f32x4;    // MFMA accumulator

__device__ inline short8 pack4(unsigned a, unsigned b, unsigned c, unsigned d) {
    union { uint4 u; short8 s; } un;
    un.u = make_uint4(a, b, c, d);
    return un.s;
}

__device__ inline short8 as_short8(uint4 u) {
    union { uint4 u4; short8 s; } un;
    un.u4 = u;
    return un.s;
}

__device__ inline unsigned rne_bf16(float v) {   // round-to-nearest-even, high16
    unsigned u = __float_as_uint(v);
    return (u + 0x7FFFu + ((u >> 16) & 1u)) >> 16;
}

// ---------------- CSR 1: per-block bucket histogram (also zeroes `done`) ----
__global__ __launch_bounds__(256) void bucket_count(
    const int* __restrict__ dst, int* __restrict__ cnt, int* __restrict__ done,
    int E, int NBUCK) {
    extern __shared__ int hist[];   // NBUCK ints
    const int b = blockIdx.x;
    if (b == 0 && threadIdx.x == 0) *done = 0;   // reset for prescan_toff
    const int per = (E + NBA - 1) / NBA;
    const int lo = b * per, hi = min(lo + per, E);
    for (int k = threadIdx.x; k < NBUCK; k += 256) hist[k] = 0;
    __syncthreads();
    for (int e = lo + threadIdx.x; e < hi; e += 256)
        atomicAdd(&hist[dst[e] >> 8], 1);
    __syncthreads();
    for (int k = threadIdx.x; k < NBUCK; k += 256)
        cnt[b * NBUCK + k] = hist[k];
}

// ---------------- CSR 2: per-bucket wave scan + last-block bucket-offs scan -
__global__ __launch_bounds__(256) void bucket_prescan_toff(
    const int* __restrict__ cnt, int* __restrict__ base, int* __restrict__ tot,
    int* __restrict__ boff, int* __restrict__ offs, int* __restrict__ done,
    int NBUCK, int E, int N) {
    const int lane = threadIdx.x & 63;
    const int k = (int)((blockIdx.x * 256 + threadIdx.x) >> 6);
    if (k < NBUCK) {
        int v0 = cnt[(size_t)lane * NBUCK + k];
        int v1 = cnt[(size_t)(lane + 64) * NBUCK + k];
        int s0 = v0, s1 = v1;
#pragma unroll
        for (int o = 1; o < 64; o <<= 1) {
            const int u0 = __shfl_up(s0, o, 64);
            const int u1 = __shfl_up(s1, o, 64);
            if (lane >= o) { s0 += u0; s1 += u1; }
        }
        const int total0 = __shfl(s0, 63, 64);
        base[(size_t)lane * NBUCK + k] = s0 - v0;                 // exclusive
        base[(size_t)(lane + 64) * NBUCK + k] = total0 + s1 - v1;
        if (lane == 63) tot[k] = total0 + s1;
    }
    __threadfence();                     // make tot/base visible device-wide
    __shared__ int lastflag;
    if (threadIdx.x == 0)
        lastflag = (atomicAdd(done, 1) == (int)gridDim.x - 1);
    __syncthreads();
    if (!lastflag) return;
    __threadfence();                     // acquire side

    // exclusive scan over NBUCK bucket totals (this block only)
    __shared__ int s[256];
    __shared__ int carry_s;
    const int t = threadIdx.x;
    if (t == 0) carry_s = 0;
    __syncthreads();
    for (int cs = 0; cs < NBUCK; cs += 256) {
        const int i = cs + t;
        const int v = (i < NBUCK) ? tot[i] : 0;
        s[t] = v;
        __syncthreads();
        for (int o = 1; o < 256; o <<= 1) {
            const int a = (t >= o) ? s[t - o] : 0;
            __syncthreads();
            s[t] += a;
            __syncthreads();
        }
        const int c0 = carry_s;
        if (i < NBUCK) boff[i] = c0 + s[t] - v;
        __syncthreads();
        if (t == 255) carry_s = c0 + s[255];
        __syncthreads();
    }
    if (t == 0) { boff[NBUCK] = E; offs[N] = E; }
}

// ---------------- CSR 3: packed scatter into block-private runs -------------
__global__ __launch_bounds__(256) void bucket_scatter(
    const int* __restrict__ src, const int* __restrict__ dst,
    const int* __restrict__ base, const int* __restrict__ boff,
    unsigned* __restrict__ ebuf, int E, int NBUCK) {
    extern __shared__ int pos[];   // NBUCK ints
    const int b = blockIdx.x;
    const int per = (E + NBA - 1) / NBA;
    const int lo = b * per, hi = min(lo + per, E);
    for (int k = threadIdx.x; k < NBUCK; k += 256)
        pos[k] = base[b * NBUCK + k] + boff[k];
    __syncthreads();
    for (int e = lo + threadIdx.x; e < hi; e += 256) {
        const int d = dst[e];
        const int s = src[e];
        const int p = atomicAdd(&pos[d >> 8], 1);          // LDS only
        ebuf[p] = ((unsigned)(d & 255) << 24) | (unsigned)s;
    }
}

// ---------------- CSR 4: per-bucket LDS counting sort -----------------------
__global__ __launch_bounds__(256) void bucket_sort(
    const unsigned* __restrict__ ebuf, const int* __restrict__ boff,
    int* __restrict__ offs, int* __restrict__ adj, int N) {
    const int b  = blockIdx.x;
    const int lo = boff[b];
    const int sz = boff[b + 1] - lo;
    const int base = b << 8;
    const int t = threadIdx.x;

    __shared__ int hist[256];
    __shared__ int hcur[256];
    __shared__ unsigned sbuf[CAP];

    hist[t] = 0;
    __syncthreads();
    for (int i = t; i < sz; i += 256)
        atomicAdd(&hist[ebuf[lo + i] >> 24], 1);
    __syncthreads();
    int v = hist[t];
    hcur[t] = v;
    __syncthreads();
    for (int o = 1; o < 256; o <<= 1) {
        const int a = (t >= o) ? hcur[t - o] : 0;
        __syncthreads();
        hcur[t] += a;
        __syncthreads();
    }
    const int ex = hcur[t] - v;
    __syncthreads();
    hcur[t] = ex;
    if (base + t < N) offs[base + t] = lo + ex;
    __syncthreads();

    if (sz <= CAP) {
        for (int i = t; i < sz; i += 256) {
            const unsigned w = ebuf[lo + i];
            const int p = atomicAdd(&hcur[w >> 24], 1);
            sbuf[p] = w & 0x00FFFFFFu;
        }
        __syncthreads();
        for (int i = t; i < sz; i += 256) adj[lo + i] = (int)sbuf[i];   // coalesced
    } else {                          // skew fallback (correct, uncoalesced)
        for (int i = t; i < sz; i += 256) {
            const unsigned w = ebuf[lo + i];
            const int p = atomicAdd(&hcur[w >> 24], 1);
            adj[lo + p] = (int)(w & 0x00FFFFFFu);
        }
    }
}

// ---------------- prep: pack_B (first blocks) + cast_bf16 (rest) ------------
__global__ __launch_bounds__(256) void prep(
    const float* __restrict__ Wl, const float* __restrict__ Wr,
    unsigned* __restrict__ Bp, int L,
    const float* __restrict__ x, unsigned short* __restrict__ bfIn,
    long long n8, int packBlocks) {
    if ((int)blockIdx.x < packBlocks) {
        // ---- pack W into MFMA B-fragment layout, bf16 hi/lo ----
        int t = blockIdx.x * 256 + threadIdx.x;
        int wv = t >> 6, lane = t & 63;
        if (wv >= L * 16) return;
        int layer = wv >> 4;
        int fid = wv & 15;
        int ks = fid >> 2, nt = fid & 3;
        int j = nt * 16 + (lane & 15);
        int kb = ks * 32 + (lane >> 4) * 8;
        const float* wl = Wl + (size_t)layer * DD * DD;
        const float* wr = Wr + (size_t)layer * DD * DD;
        unsigned hi[8], lo[8];
#pragma unroll
        for (int s = 0; s < 8; ++s) {
            int k = kb + s;
            float v = (k < DD) ? wl[k * DD + j] : wr[(k - DD) * DD + j];
            unsigned u = __float_as_uint(v);
            unsigned h = u & 0xFFFF0000u;
            hi[s] = h;
            float lf = v - __uint_as_float(h);         // exact residual
            lo[s] = __float_as_uint(lf) & 0xFFFF0000u;
        }
        size_t base_hi = ((size_t)(layer * 2 + 0) * 16 + fid) * 64 + lane;
        size_t base_lo = ((size_t)(layer * 2 + 1) * 16 + fid) * 64 + lane;
#pragma unroll
        for (int p = 0; p < 4; ++p) {
            Bp[base_hi * 4 + p] = (hi[2 * p] >> 16) | hi[2 * p + 1];
            Bp[base_lo * 4 + p] = (lo[2 * p] >> 16) | lo[2 * p + 1];
        }
    } else {
        // ---- fp32 -> bf16 (RNE) cast, 8 elems/thread ----
        const long long t = (long long)(blockIdx.x - packBlocks) * 256 + threadIdx.x;
        if (t >= n8) return;
        const float4 v0 = *reinterpret_cast<const float4*>(x + t * 8);
        const float4 v1 = *reinterpret_cast<const float4*>(x + t * 8 + 4);
        uint4 o;
        o.x = rne_bf16(v0.x) | (rne_bf16(v0.y) << 16);
        o.y = rne_bf16(v0.z) | (rne_bf16(v0.w) << 16);
        o.z = rne_bf16(v1.x) | (rne_bf16(v1.y) << 16);
        o.w = rne_bf16(v1.z) | (rne_bf16(v1.w) << 16);
        *reinterpret_cast<uint4*>(bfIn + t * 8) = o;
    }
}

// ---------------- gather-mean bf16: ONE WAVE PER NODE ----------------
// lane = eslot*8 + dchunk. eslot e handles edges j == e (mod 8); dchunk owns
// 8 dims (16B). Uniform ceil(deg/8) iterations -> no cross-node divergence.
#define ACC8(A, U)                                                             \
    do {                                                                       \
        A[0] += __uint_as_float((U).x << 16);                                  \
        A[1] += __uint_as_float((U).x & 0xFFFF0000u);                          \
        A[2] += __uint_as_float((U).y << 16);                                  \
        A[3] += __uint_as_float((U).y & 0xFFFF0000u);                          \
        A[4] += __uint_as_float((U).z << 16);                                  \
        A[5] += __uint_as_float((U).z & 0xFFFF0000u);                          \
        A[6] += __uint_as_float((U).w << 16);                                  \
        A[7] += __uint_as_float((U).w & 0xFFFF0000u);                          \
    } while (0)

__global__ __launch_bounds__(256) void aggregate_bf16(
    const unsigned short* __restrict__ xb, unsigned short* __restrict__ aggb,
    const int* __restrict__ offs, const int* __restrict__ adj, int n) {
    const int lane  = threadIdx.x & 63;
    const int nd    = (int)((blockIdx.x * 256 + threadIdx.x) >> 6);
    if (nd >= n) return;
    const int eslot = lane >> 3;
    const int c8    = (lane & 7) * 8;

    const int s = offs[nd];
    const int e = offs[nd + 1];

    float a[8];
#pragma unroll
    for (int p = 0; p < 8; ++p) a[p] = 0.f;

    for (int j = s + eslot; j < e; j += 8) {
        const uint4 u = *reinterpret_cast<const uint4*>(xb + (size_t)adj[j] * DD + c8);
        ACC8(a, u);
    }

    // reduce across the 8 eslots (lanes with same dchunk)
#pragma unroll
    for (int mask = 8; mask <= 32; mask <<= 1) {
#pragma unroll
        for (int p = 0; p < 8; ++p) a[p] += __shfl_xor(a[p], mask, 64);
    }

    if (eslot == 0) {
        const int deg = e - s;
        const float inv = (deg > 0) ? (1.0f / (float)deg) : 1.0f;
#pragma unroll
        for (int p = 0; p < 8; ++p) a[p] *= inv;
        uint4 o;
        o.x = rne_bf16(a[0]) | (rne_bf16(a[1]) << 16);
        o.y = rne_bf16(a[2]) | (rne_bf16(a[3]) << 16);
        o.z = rne_bf16(a[4]) | (rne_bf16(a[5]) << 16);
        o.w = rne_bf16(a[6]) | (rne_bf16(a[7]) << 16);
        *reinterpret_cast<uint4*>(aggb + (size_t)nd * DD + c8) = o;  // 8 lanes, 128B
    }
}

// ---------------- layer GEMM: outb = bias + aggb@Wl + xb@Wr (all bf16 A) ----
__global__ __launch_bounds__(256, 2) void mfma_gemm(
    const unsigned short* __restrict__ gb, const unsigned short* __restrict__ xb,
    unsigned short* __restrict__ outb, const unsigned* __restrict__ Bp,
    const float* __restrict__ bias, int n) {
    const int lane = threadIdx.x & 63;
    const int wv   = (int)((blockIdx.x * 256 + threadIdx.x) >> 6);
    const int nwv  = (int)((gridDim.x * 256) >> 6);

    short8 Bh[4][4], Bl[4][4];
#pragma unroll
    for (int ks = 0; ks < 4; ++ks)
#pragma unroll
        for (int nt = 0; nt < 4; ++nt) {
            int fid = ks * 4 + nt;
            const uint4 h = *reinterpret_cast<const uint4*>(Bp + ((size_t)fid * 64 + lane) * 4);
            const uint4 l = *reinterpret_cast<const uint4*>(Bp + ((size_t)(16 + fid) * 64 + lane) * 4);
            Bh[ks][nt] = pack4(h.x, h.y, h.z, h.w);
            Bl[ks][nt] = pack4(l.x, l.y, l.z, l.w);
        }

    float bv[4];
#pragma unroll
    for (int nt = 0; nt < 4; ++nt) bv[nt] = bias[nt * 16 + (lane & 15)];

    const int ntiles = (n + 15) >> 4;
    for (int tile = wv; tile < ntiles; tile += nwv) {
        const int row = tile * 16 + (lane & 15);
        const bool ok = row < n;
        const unsigned short* grow = gb + (size_t)row * DD + (lane >> 4) * 8;
        const unsigned short* xrow = xb + (size_t)row * DD + (lane >> 4) * 8;

        f32x4 acc[4];
#pragma unroll
        for (int nt = 0; nt < 4; ++nt) acc[nt] = (f32x4){bv[nt], bv[nt], bv[nt], bv[nt]};

#pragma unroll
        for (int ks = 0; ks < 4; ++ks) {
            const unsigned short* base = ((ks < 2) ? grow : xrow) + (ks & 1) * 32;
            const uint4 u = ok ? *reinterpret_cast<const uint4*>(base)
                               : make_uint4(0, 0, 0, 0);
            const short8 Ah = as_short8(u);
#pragma unroll
            for (int nt = 0; nt < 4; ++nt) {
                acc[nt] = __builtin_amdgcn_mfma_f32_16x16x32_bf16(Ah, Bh[ks][nt], acc[nt], 0, 0, 0);
                acc[nt] = __builtin_amdgcn_mfma_f32_16x16x32_bf16(Ah, Bl[ks][nt], acc[nt], 0, 0, 0);
            }
        }

        // C/D layout (verified): col = lane&15, row = (lane>>4)*4 + reg
        const int r0 = tile * 16 + (lane >> 4) * 4;
#pragma unroll
        for (int r = 0; r < 4; ++r) {
            const int rr = r0 + r;
            if (rr < n) {
#pragma unroll
                for (int nt = 0; nt < 4; ++nt) {
                    const size_t idx = (size_t)rr * DD + nt * 16 + (lane & 15);
                    outb[idx] = (unsigned short)rne_bf16(acc[nt][r]);
                }
            }
        }
    }
}

// ---------------- pooling partials over TWO bf16 arrays ----------------
__global__ __launch_bounds__(256) void pool_partial2(
    const unsigned short* __restrict__ xa, const unsigned short* __restrict__ xb,
    const int* __restrict__ batch,
    float* __restrict__ sumsA, float* __restrict__ sumsB, int n) {
    const int lane = threadIdx.x & 63;
    const int wv   = (int)((blockIdx.x * blockDim.x + threadIdx.x) >> 6);
    const int nwv  = (int)((gridDim.x * blockDim.x) >> 6);
    const int chunk = (n + nwv - 1) / nwv;
    const int start = wv * chunk;
    if (start >= n) return;
    const int end = min(start + chunk, n);

    int g = batch[start];
    float accA = 0.f, accB = 0.f;
    for (int nd = start; nd < end; ++nd) {
        const int bg = batch[nd];
        if (bg != g) {
            atomicAdd(&sumsA[(size_t)g * DD + lane], accA);
            atomicAdd(&sumsB[(size_t)g * DD + lane], accB);
            accA = 0.f; accB = 0.f;
            g = bg;
        }
        accA += __uint_as_float((unsigned)xa[(size_t)nd * DD + lane] << 16);
        accB += __uint_as_float((unsigned)xb[(size_t)nd * DD + lane] << 16);
    }
    atomicAdd(&sumsA[(size_t)g * DD + lane], accA);
    atomicAdd(&sumsB[(size_t)g * DD + lane], accB);
}

// ---------------- final: out[g] = mean(agg3)@Wl + mean(x2)@Wr + b ----------
__global__ void final_gemm(const float* __restrict__ sumsA, const float* __restrict__ sumsX,
                           const int* __restrict__ batch,
                           const float* __restrict__ Wl, const float* __restrict__ bl,
                           const float* __restrict__ Wr,
                           float* __restrict__ out, int n) {
    const int g = blockIdx.x;
    const int d = threadIdx.x;  // 64 threads

    int lo = 0, hi = n;
    while (lo < hi) { int m = (lo + hi) >> 1; if (batch[m] < g) lo = m + 1; else hi = m; }
    const int st = lo;
    lo = 0; hi = n;
    while (lo < hi) { int m = (lo + hi) >> 1; if (batch[m] < g + 1) lo = m + 1; else hi = m; }
    const int c = lo - st;

    if (c == 0) {                    // reference: empty graph -> 0 (not bias)
        out[(size_t)g * DD + d] = 0.f;
        return;
    }
    const float inv = 1.0f / (float)c;

    __shared__ float sa[DD], sx[DD];
    sa[d] = sumsA[(size_t)g * DD + d] * inv;
    sx[d] = sumsX[(size_t)g * DD + d] * inv;
    __syncthreads();

    float acc = bl[d];
#pragma unroll 8
    for (int k = 0; k < DD; ++k) acc += sa[k] * Wl[k * DD + d];
#pragma unroll 8
    for (int k = 0; k < DD; ++k) acc += sx[k] * Wr[k * DD + d];
    out[(size_t)g * DD + d] = acc;
}

extern "C" void kernel_launch(void* const* d_in, const int* in_sizes, int n_in,
                              void* d_out, int out_size, void* d_ws, size_t ws_size,
                              hipStream_t stream) {
    const float* x     = (const float*)d_in[0];
    const int*   ei    = (const int*)d_in[1];
    const int*   batch = (const int*)d_in[2];
    const float* Wl    = (const float*)d_in[3];
    const float* bl    = (const float*)d_in[4];
    const float* Wr    = (const float*)d_in[5];

    const int N = in_sizes[0] / DD;
    const int E = in_sizes[1] / 2;
    const int L = in_sizes[3] / (DD * DD);
    const int G = out_size / DD;
    const int NBUCK = (N + 255) >> 8;          // 256-node buckets

    const int* src = ei;        // edge_index[0]
    const int* dst = ei + E;    // edge_index[1]

    char* ws = (char*)d_ws;
    size_t off = 0;
    auto alloc = [&](size_t bytes) -> char* {
        char* p = ws + off;
        off += (bytes + 255) & ~(size_t)255;
        return p;
    };
    int*      offs   = (int*)alloc((size_t)(N + 1) * 4);
    int*      adj    = (int*)alloc((size_t)E * 4);
    int*      cnt    = (int*)alloc((size_t)NBA * NBUCK * 4);
    int*      basep  = (int*)alloc((size_t)NBA * NBUCK * 4);
    int*      boff   = (int*)alloc((size_t)(NBUCK + 1) * 4);
    int*      tot    = (int*)alloc((size_t)NBUCK * 4);
    int*      done   = (int*)alloc(256);
    unsigned* ebuf   = (unsigned*)alloc((size_t)E * 4);
    const size_t bfbytes = (size_t)N * DD * 2;
    unsigned short* aggb = (unsigned short*)alloc(bfbytes);   // bf16 agg
    unsigned* Bp     = (unsigned*)alloc((size_t)L * 2 * 16 * 64 * 4 * 4);
    float*    sumsA  = (float*)alloc((size_t)G * DD * 4);    // adjacent with sumsX
    float*    sumsX  = (float*)alloc((size_t)G * DD * 4);
    unsigned short* bfIn = (unsigned short*)alloc(bfbytes);   // cast(x); reused layer-1 out
    unsigned short* bf0  = (unsigned short*)alloc(bfbytes);   // layer-0 out

    // ---- CSR build: all-coalesced counting sort (4 dispatches) ----
    const size_t ldsN = (size_t)NBUCK * 4;
    bucket_count<<<NBA, 256, ldsN, stream>>>(dst, cnt, done, E, NBUCK);
    const int preBlocks = (NBUCK * 64 + 255) / 256;
    bucket_prescan_toff<<<preBlocks, 256, 0, stream>>>(cnt, basep, tot, boff, offs,
                                                       done, NBUCK, E, N);
    bucket_scatter<<<NBA, 256, ldsN, stream>>>(src, dst, basep, boff, ebuf, E, NBUCK);
    bucket_sort<<<NBUCK, 256, 0, stream>>>(ebuf, boff, offs, adj, N);

    // ---- prep: pack W frags + cast x to bf16 (one dispatch) ----
    const long long n8 = (long long)N * DD / 8;
    const int packBlocks = (L * 16 * 64 + 255) / 256;
    prep<<<packBlocks + (int)((n8 + 255) / 256), 256, 0, stream>>>(
        Wl, Wr, Bp, L, x, bfIn, n8, packBlocks);

    // ---- layers 0..L-2: aggregate + MFMA gemm (bf16 ping-pong) ----
    const unsigned short* curb = bfIn;
    unsigned short* bfs[2] = {bf0, bfIn};   // layer 0 -> bf0, layer 1 -> bfIn (dead)
    const int agg_blocks = (int)(((long long)N * 64 + 255) / 256);   // 1 wave/node
    for (int l = 0; l < L - 1; ++l) {
        aggregate_bf16<<<agg_blocks, 256, 0, stream>>>(curb, aggb, offs, adj, N);
        mfma_gemm<<<1024, 256, 0, stream>>>(aggb, curb, bfs[l & 1],
                                            Bp + (size_t)l * 2 * 16 * 64 * 4,
                                            bl + (size_t)l * DD, N);
        curb = bfs[l & 1];
    }

    // ---- last layer: pooling is linear -> pool(agg), pool(x), tiny GEMM ----
    aggregate_bf16<<<agg_blocks, 256, 0, stream>>>(curb, aggb, offs, adj, N);
    (void)hipMemsetAsync(sumsA, 0, (size_t)G * DD * 4 * 2, stream);   // sumsA+sumsX adjacent
    pool_partial2<<<2048, 256, 0, stream>>>(aggb, curb, batch, sumsA, sumsX, N);
    final_gemm<<<G, DD, 0, stream>>>(sumsA, sumsX, batch,
                                     Wl + (size_t)(L - 1) * DD * DD,
                                     bl + (size_t)(L - 1) * DD,
                                     Wr + (size_t)(L - 1) * DD * DD,
                                     (float*)d_out, N);
}

// Round 18
// 186.149 us; speedup vs baseline: 1.1403x; 1.1403x over previous
//
#include <hip/hip_runtime.h>

// GraphSAGE (mean) x3 + per-graph mean pool, MI355X.
// R18: revert R17's wave-per-node gather (cut per-lane MLP 8->1 outstanding
// loads; latency-bound gather needs MLP more than divergence smoothing:
// 212us vs 187us at equal machine speed). Final structure = R16:
//  - CSR: all-coalesced counting sort (count -> prescan+toff fused ->
//    private-run scatter -> per-bucket LDS sort), no scattered global writes.
//  - prep: pack_B (bf16 hi/lo W frags) + cast x->bf16, one dispatch.
//  - per layer: 8thr/node 8-deep gather (bf16 in/out) + MFMA gemm (bf16 A
//    direct, W hi/lo split, bf16 out).
//  - last layer: pooling linearity -> pool(agg,x) + 64x128x64 final gemm.

#define DD 64
#define NBA 128    // blocks in count/scatter passes (= 2 x wave width)
#define CAP 4096   // per-bucket LDS sort capacity (avg bucket ~2560 edges)

typedef __attribute__((ext_vector_type(8))) short short8;   // 8 bf16 (4 VGPRs)
typedef __attribute__((ext_vector_type(4))) float f32x4;    // MFMA accumulator

__device__ inline short8 pack4(unsigned a, unsigned b, unsigned c, unsigned d) {
    union { uint4 u; short8 s; } un;
    un.u = make_uint4(a, b, c, d);
    return un.s;
}

__device__ inline short8 as_short8(uint4 u) {
    union { uint4 u4; short8 s; } un;
    un.u4 = u;
    return un.s;
}

__device__ inline unsigned rne_bf16(float v) {   // round-to-nearest-even, high16
    unsigned u = __float_as_uint(v);
    return (u + 0x7FFFu + ((u >> 16) & 1u)) >> 16;
}

// ---------------- CSR 1: per-block bucket histogram (also zeroes `done`) ----
__global__ __launch_bounds__(256) void bucket_count(
    const int* __restrict__ dst, int* __restrict__ cnt, int* __restrict__ done,
    int E, int NBUCK) {
    extern __shared__ int hist[];   // NBUCK ints
    const int b = blockIdx.x;
    if (b == 0 && threadIdx.x == 0) *done = 0;   // reset for prescan_toff
    const int per = (E + NBA - 1) / NBA;
    const int lo = b * per, hi = min(lo + per, E);
    for (int k = threadIdx.x; k < NBUCK; k += 256) hist[k] = 0;
    __syncthreads();
    for (int e = lo + threadIdx.x; e < hi; e += 256)
        atomicAdd(&hist[dst[e] >> 8], 1);
    __syncthreads();
    for (int k = threadIdx.x; k < NBUCK; k += 256)
        cnt[b * NBUCK + k] = hist[k];
}

// ---------------- CSR 2: per-bucket wave scan + last-block bucket-offs scan -
__global__ __launch_bounds__(256) void bucket_prescan_toff(
    const int* __restrict__ cnt, int* __restrict__ base, int* __restrict__ tot,
    int* __restrict__ boff, int* __restrict__ offs, int* __restrict__ done,
    int NBUCK, int E, int N) {
    const int lane = threadIdx.x & 63;
    const int k = (int)((blockIdx.x * 256 + threadIdx.x) >> 6);
    if (k < NBUCK) {
        int v0 = cnt[(size_t)lane * NBUCK + k];
        int v1 = cnt[(size_t)(lane + 64) * NBUCK + k];
        int s0 = v0, s1 = v1;
#pragma unroll
        for (int o = 1; o < 64; o <<= 1) {
            const int u0 = __shfl_up(s0, o, 64);
            const int u1 = __shfl_up(s1, o, 64);
            if (lane >= o) { s0 += u0; s1 += u1; }
        }
        const int total0 = __shfl(s0, 63, 64);
        base[(size_t)lane * NBUCK + k] = s0 - v0;                 // exclusive
        base[(size_t)(lane + 64) * NBUCK + k] = total0 + s1 - v1;
        if (lane == 63) tot[k] = total0 + s1;
    }
    __threadfence();                     // make tot/base visible device-wide
    __shared__ int lastflag;
    if (threadIdx.x == 0)
        lastflag = (atomicAdd(done, 1) == (int)gridDim.x - 1);
    __syncthreads();
    if (!lastflag) return;
    __threadfence();                     // acquire side

    // exclusive scan over NBUCK bucket totals (this block only)
    __shared__ int s[256];
    __shared__ int carry_s;
    const int t = threadIdx.x;
    if (t == 0) carry_s = 0;
    __syncthreads();
    for (int cs = 0; cs < NBUCK; cs += 256) {
        const int i = cs + t;
        const int v = (i < NBUCK) ? tot[i] : 0;
        s[t] = v;
        __syncthreads();
        for (int o = 1; o < 256; o <<= 1) {
            const int a = (t >= o) ? s[t - o] : 0;
            __syncthreads();
            s[t] += a;
            __syncthreads();
        }
        const int c0 = carry_s;
        if (i < NBUCK) boff[i] = c0 + s[t] - v;
        __syncthreads();
        if (t == 255) carry_s = c0 + s[255];
        __syncthreads();
    }
    if (t == 0) { boff[NBUCK] = E; offs[N] = E; }
}

// ---------------- CSR 3: packed scatter into block-private runs -------------
__global__ __launch_bounds__(256) void bucket_scatter(
    const int* __restrict__ src, const int* __restrict__ dst,
    const int* __restrict__ base, const int* __restrict__ boff,
    unsigned* __restrict__ ebuf, int E, int NBUCK) {
    extern __shared__ int pos[];   // NBUCK ints
    const int b = blockIdx.x;
    const int per = (E + NBA - 1) / NBA;
    const int lo = b * per, hi = min(lo + per, E);
    for (int k = threadIdx.x; k < NBUCK; k += 256)
        pos[k] = base[b * NBUCK + k] + boff[k];
    __syncthreads();
    for (int e = lo + threadIdx.x; e < hi; e += 256) {
        const int d = dst[e];
        const int s = src[e];
        const int p = atomicAdd(&pos[d >> 8], 1);          // LDS only
        ebuf[p] = ((unsigned)(d & 255) << 24) | (unsigned)s;
    }
}

// ---------------- CSR 4: per-bucket LDS counting sort -----------------------
__global__ __launch_bounds__(256) void bucket_sort(
    const unsigned* __restrict__ ebuf, const int* __restrict__ boff,
    int* __restrict__ offs, int* __restrict__ adj, int N) {
    const int b  = blockIdx.x;
    const int lo = boff[b];
    const int sz = boff[b + 1] - lo;
    const int base = b << 8;
    const int t = threadIdx.x;

    __shared__ int hist[256];
    __shared__ int hcur[256];
    __shared__ unsigned sbuf[CAP];

    hist[t] = 0;
    __syncthreads();
    for (int i = t; i < sz; i += 256)
        atomicAdd(&hist[ebuf[lo + i] >> 24], 1);
    __syncthreads();
    int v = hist[t];
    hcur[t] = v;
    __syncthreads();
    for (int o = 1; o < 256; o <<= 1) {
        const int a = (t >= o) ? hcur[t - o] : 0;
        __syncthreads();
        hcur[t] += a;
        __syncthreads();
    }
    const int ex = hcur[t] - v;
    __syncthreads();
    hcur[t] = ex;
    if (base + t < N) offs[base + t] = lo + ex;
    __syncthreads();

    if (sz <= CAP) {
        for (int i = t; i < sz; i += 256) {
            const unsigned w = ebuf[lo + i];
            const int p = atomicAdd(&hcur[w >> 24], 1);
            sbuf[p] = w & 0x00FFFFFFu;
        }
        __syncthreads();
        for (int i = t; i < sz; i += 256) adj[lo + i] = (int)sbuf[i];   // coalesced
    } else {                          // skew fallback (correct, uncoalesced)
        for (int i = t; i < sz; i += 256) {
            const unsigned w = ebuf[lo + i];
            const int p = atomicAdd(&hcur[w >> 24], 1);
            adj[lo + p] = (int)(w & 0x00FFFFFFu);
        }
    }
}

// ---------------- prep: pack_B (first blocks) + cast_bf16 (rest) ------------
__global__ __launch_bounds__(256) void prep(
    const float* __restrict__ Wl, const float* __restrict__ Wr,
    unsigned* __restrict__ Bp, int L,
    const float* __restrict__ x, unsigned short* __restrict__ bfIn,
    long long n8, int packBlocks) {
    if ((int)blockIdx.x < packBlocks) {
        // ---- pack W into MFMA B-fragment layout, bf16 hi/lo ----
        int t = blockIdx.x * 256 + threadIdx.x;
        int wv = t >> 6, lane = t & 63;
        if (wv >= L * 16) return;
        int layer = wv >> 4;
        int fid = wv & 15;
        int ks = fid >> 2, nt = fid & 3;
        int j = nt * 16 + (lane & 15);
        int kb = ks * 32 + (lane >> 4) * 8;
        const float* wl = Wl + (size_t)layer * DD * DD;
        const float* wr = Wr + (size_t)layer * DD * DD;
        unsigned hi[8], lo[8];
#pragma unroll
        for (int s = 0; s < 8; ++s) {
            int k = kb + s;
            float v = (k < DD) ? wl[k * DD + j] : wr[(k - DD) * DD + j];
            unsigned u = __float_as_uint(v);
            unsigned h = u & 0xFFFF0000u;
            hi[s] = h;
            float lf = v - __uint_as_float(h);         // exact residual
            lo[s] = __float_as_uint(lf) & 0xFFFF0000u;
        }
        size_t base_hi = ((size_t)(layer * 2 + 0) * 16 + fid) * 64 + lane;
        size_t base_lo = ((size_t)(layer * 2 + 1) * 16 + fid) * 64 + lane;
#pragma unroll
        for (int p = 0; p < 4; ++p) {
            Bp[base_hi * 4 + p] = (hi[2 * p] >> 16) | hi[2 * p + 1];
            Bp[base_lo * 4 + p] = (lo[2 * p] >> 16) | lo[2 * p + 1];
        }
    } else {
        // ---- fp32 -> bf16 (RNE) cast, 8 elems/thread ----
        const long long t = (long long)(blockIdx.x - packBlocks) * 256 + threadIdx.x;
        if (t >= n8) return;
        const float4 v0 = *reinterpret_cast<const float4*>(x + t * 8);
        const float4 v1 = *reinterpret_cast<const float4*>(x + t * 8 + 4);
        uint4 o;
        o.x = rne_bf16(v0.x) | (rne_bf16(v0.y) << 16);
        o.y = rne_bf16(v0.z) | (rne_bf16(v0.w) << 16);
        o.z = rne_bf16(v1.x) | (rne_bf16(v1.y) << 16);
        o.w = rne_bf16(v1.z) | (rne_bf16(v1.w) << 16);
        *reinterpret_cast<uint4*>(bfIn + t * 8) = o;
    }
}

// ---------------- gather-mean bf16 -> bf16 (8 threads/node, 8-deep) --------
#define ACC8(A, U)                                                             \
    do {                                                                       \
        A[0] += __uint_as_float((U).x << 16);                                  \
        A[1] += __uint_as_float((U).x & 0xFFFF0000u);                          \
        A[2] += __uint_as_float((U).y << 16);                                  \
        A[3] += __uint_as_float((U).y & 0xFFFF0000u);                          \
        A[4] += __uint_as_float((U).z << 16);                                  \
        A[5] += __uint_as_float((U).z & 0xFFFF0000u);                          \
        A[6] += __uint_as_float((U).w << 16);                                  \
        A[7] += __uint_as_float((U).w & 0xFFFF0000u);                          \
    } while (0)

__global__ __launch_bounds__(256) void aggregate_bf16(
    const unsigned short* __restrict__ xb, unsigned short* __restrict__ aggb,
    const int* __restrict__ offs, const int* __restrict__ adj, int n) {
    const int t  = blockIdx.x * 256 + threadIdx.x;
    const int nd = t >> 3;
    const int c8 = (t & 7) * 8;
    if (nd >= n) return;

    const int s = offs[nd];
    const int e = offs[nd + 1];

    float a0[8], a1[8], a2[8], a3[8];
#pragma unroll
    for (int p = 0; p < 8; ++p) { a0[p] = 0.f; a1[p] = 0.f; a2[p] = 0.f; a3[p] = 0.f; }

    int j = s;
    for (; j + 8 <= e; j += 8) {        // 8 outstanding row loads
        const int i0 = adj[j],     i1 = adj[j + 1], i2 = adj[j + 2], i3 = adj[j + 3];
        const int i4 = adj[j + 4], i5 = adj[j + 5], i6 = adj[j + 6], i7 = adj[j + 7];
        const uint4 u0 = *reinterpret_cast<const uint4*>(xb + (size_t)i0 * DD + c8);
        const uint4 u1 = *reinterpret_cast<const uint4*>(xb + (size_t)i1 * DD + c8);
        const uint4 u2 = *reinterpret_cast<const uint4*>(xb + (size_t)i2 * DD + c8);
        const uint4 u3 = *reinterpret_cast<const uint4*>(xb + (size_t)i3 * DD + c8);
        const uint4 u4 = *reinterpret_cast<const uint4*>(xb + (size_t)i4 * DD + c8);
        const uint4 u5 = *reinterpret_cast<const uint4*>(xb + (size_t)i5 * DD + c8);
        const uint4 u6 = *reinterpret_cast<const uint4*>(xb + (size_t)i6 * DD + c8);
        const uint4 u7 = *reinterpret_cast<const uint4*>(xb + (size_t)i7 * DD + c8);
        ACC8(a0, u0); ACC8(a1, u1); ACC8(a2, u2); ACC8(a3, u3);
        ACC8(a0, u4); ACC8(a1, u5); ACC8(a2, u6); ACC8(a3, u7);
    }
    for (; j + 4 <= e; j += 4) {
        const int i0 = adj[j], i1 = adj[j + 1], i2 = adj[j + 2], i3 = adj[j + 3];
        const uint4 u0 = *reinterpret_cast<const uint4*>(xb + (size_t)i0 * DD + c8);
        const uint4 u1 = *reinterpret_cast<const uint4*>(xb + (size_t)i1 * DD + c8);
        const uint4 u2 = *reinterpret_cast<const uint4*>(xb + (size_t)i2 * DD + c8);
        const uint4 u3 = *reinterpret_cast<const uint4*>(xb + (size_t)i3 * DD + c8);
        ACC8(a0, u0); ACC8(a1, u1); ACC8(a2, u2); ACC8(a3, u3);
    }
    for (; j < e; ++j) {
        const uint4 u = *reinterpret_cast<const uint4*>(xb + (size_t)adj[j] * DD + c8);
        ACC8(a0, u);
    }

    const int deg = e - s;
    const float inv = (deg > 0) ? (1.0f / (float)deg) : 1.0f;
    float r[8];
#pragma unroll
    for (int p = 0; p < 8; ++p) r[p] = (a0[p] + a1[p] + a2[p] + a3[p]) * inv;
    uint4 o;
    o.x = rne_bf16(r[0]) | (rne_bf16(r[1]) << 16);
    o.y = rne_bf16(r[2]) | (rne_bf16(r[3]) << 16);
    o.z = rne_bf16(r[4]) | (rne_bf16(r[5]) << 16);
    o.w = rne_bf16(r[6]) | (rne_bf16(r[7]) << 16);
    *reinterpret_cast<uint4*>(aggb + (size_t)nd * DD + c8) = o;
}

// ---------------- layer GEMM: outb = bias + aggb@Wl + xb@Wr (all bf16 A) ----
__global__ __launch_bounds__(256, 2) void mfma_gemm(
    const unsigned short* __restrict__ gb, const unsigned short* __restrict__ xb,
    unsigned short* __restrict__ outb, const unsigned* __restrict__ Bp,
    const float* __restrict__ bias, int n) {
    const int lane = threadIdx.x & 63;
    const int wv   = (int)((blockIdx.x * 256 + threadIdx.x) >> 6);
    const int nwv  = (int)((gridDim.x * 256) >> 6);

    short8 Bh[4][4], Bl[4][4];
#pragma unroll
    for (int ks = 0; ks < 4; ++ks)
#pragma unroll
        for (int nt = 0; nt < 4; ++nt) {
            int fid = ks * 4 + nt;
            const uint4 h = *reinterpret_cast<const uint4*>(Bp + ((size_t)fid * 64 + lane) * 4);
            const uint4 l = *reinterpret_cast<const uint4*>(Bp + ((size_t)(16 + fid) * 64 + lane) * 4);
            Bh[ks][nt] = pack4(h.x, h.y, h.z, h.w);
            Bl[ks][nt] = pack4(l.x, l.y, l.z, l.w);
        }

    float bv[4];
#pragma unroll
    for (int nt = 0; nt < 4; ++nt) bv[nt] = bias[nt * 16 + (lane & 15)];

    const int ntiles = (n + 15) >> 4;
    for (int tile = wv; tile < ntiles; tile += nwv) {
        const int row = tile * 16 + (lane & 15);
        const bool ok = row < n;
        const unsigned short* grow = gb + (size_t)row * DD + (lane >> 4) * 8;
        const unsigned short* xrow = xb + (size_t)row * DD + (lane >> 4) * 8;

        f32x4 acc[4];
#pragma unroll
        for (int nt = 0; nt < 4; ++nt) acc[nt] = (f32x4){bv[nt], bv[nt], bv[nt], bv[nt]};

#pragma unroll
        for (int ks = 0; ks < 4; ++ks) {
            const unsigned short* base = ((ks < 2) ? grow : xrow) + (ks & 1) * 32;
            const uint4 u = ok ? *reinterpret_cast<const uint4*>(base)
                               : make_uint4(0, 0, 0, 0);
            const short8 Ah = as_short8(u);
#pragma unroll
            for (int nt = 0; nt < 4; ++nt) {
                acc[nt] = __builtin_amdgcn_mfma_f32_16x16x32_bf16(Ah, Bh[ks][nt], acc[nt], 0, 0, 0);
                acc[nt] = __builtin_amdgcn_mfma_f32_16x16x32_bf16(Ah, Bl[ks][nt], acc[nt], 0, 0, 0);
            }
        }

        // C/D layout (verified): col = lane&15, row = (lane>>4)*4 + reg
        const int r0 = tile * 16 + (lane >> 4) * 4;
#pragma unroll
        for (int r = 0; r < 4; ++r) {
            const int rr = r0 + r;
            if (rr < n) {
#pragma unroll
                for (int nt = 0; nt < 4; ++nt) {
                    const size_t idx = (size_t)rr * DD + nt * 16 + (lane & 15);
                    outb[idx] = (unsigned short)rne_bf16(acc[nt][r]);
                }
            }
        }
    }
}

// ---------------- pooling partials over TWO bf16 arrays ----------------
__global__ __launch_bounds__(256) void pool_partial2(
    const unsigned short* __restrict__ xa, const unsigned short* __restrict__ xb,
    const int* __restrict__ batch,
    float* __restrict__ sumsA, float* __restrict__ sumsB, int n) {
    const int lane = threadIdx.x & 63;
    const int wv   = (int)((blockIdx.x * blockDim.x + threadIdx.x) >> 6);
    const int nwv  = (int)((gridDim.x * blockDim.x) >> 6);
    const int chunk = (n + nwv - 1) / nwv;
    const int start = wv * chunk;
    if (start >= n) return;
    const int end = min(start + chunk, n);

    int g = batch[start];
    float accA = 0.f, accB = 0.f;
    for (int nd = start; nd < end; ++nd) {
        const int bg = batch[nd];
        if (bg != g) {
            atomicAdd(&sumsA[(size_t)g * DD + lane], accA);
            atomicAdd(&sumsB[(size_t)g * DD + lane], accB);
            accA = 0.f; accB = 0.f;
            g = bg;
        }
        accA += __uint_as_float((unsigned)xa[(size_t)nd * DD + lane] << 16);
        accB += __uint_as_float((unsigned)xb[(size_t)nd * DD + lane] << 16);
    }
    atomicAdd(&sumsA[(size_t)g * DD + lane], accA);
    atomicAdd(&sumsB[(size_t)g * DD + lane], accB);
}

// ---------------- final: out[g] = mean(agg3)@Wl + mean(x2)@Wr + b ----------
__global__ void final_gemm(const float* __restrict__ sumsA, const float* __restrict__ sumsX,
                           const int* __restrict__ batch,
                           const float* __restrict__ Wl, const float* __restrict__ bl,
                           const float* __restrict__ Wr,
                           float* __restrict__ out, int n) {
    const int g = blockIdx.x;
    const int d = threadIdx.x;  // 64 threads

    int lo = 0, hi = n;
    while (lo < hi) { int m = (lo + hi) >> 1; if (batch[m] < g) lo = m + 1; else hi = m; }
    const int st = lo;
    lo = 0; hi = n;
    while (lo < hi) { int m = (lo + hi) >> 1; if (batch[m] < g + 1) lo = m + 1; else hi = m; }
    const int c = lo - st;

    if (c == 0) {                    // reference: empty graph -> 0 (not bias)
        out[(size_t)g * DD + d] = 0.f;
        return;
    }
    const float inv = 1.0f / (float)c;

    __shared__ float sa[DD], sx[DD];
    sa[d] = sumsA[(size_t)g * DD + d] * inv;
    sx[d] = sumsX[(size_t)g * DD + d] * inv;
    __syncthreads();

    float acc = bl[d];
#pragma unroll 8
    for (int k = 0; k < DD; ++k) acc += sa[k] * Wl[k * DD + d];
#pragma unroll 8
    for (int k = 0; k < DD; ++k) acc += sx[k] * Wr[k * DD + d];
    out[(size_t)g * DD + d] = acc;
}

extern "C" void kernel_launch(void* const* d_in, const int* in_sizes, int n_in,
                              void* d_out, int out_size, void* d_ws, size_t ws_size,
                              hipStream_t stream) {
    const float* x     = (const float*)d_in[0];
    const int*   ei    = (const int*)d_in[1];
    const int*   batch = (const int*)d_in[2];
    const float* Wl    = (const float*)d_in[3];
    const float* bl    = (const float*)d_in[4];
    const float* Wr    = (const float*)d_in[5];

    const int N = in_sizes[0] / DD;
    const int E = in_sizes[1] / 2;
    const int L = in_sizes[3] / (DD * DD);
    const int G = out_size / DD;
    const int NBUCK = (N + 255) >> 8;          // 256-node buckets

    const int* src = ei;        // edge_index[0]
    const int* dst = ei + E;    // edge_index[1]

    char* ws = (char*)d_ws;
    size_t off = 0;
    auto alloc = [&](size_t bytes) -> char* {
        char* p = ws + off;
        off += (bytes + 255) & ~(size_t)255;
        return p;
    };
    int*      offs   = (int*)alloc((size_t)(N + 1) * 4);
    int*      adj    = (int*)alloc((size_t)E * 4);
    int*      cnt    = (int*)alloc((size_t)NBA * NBUCK * 4);
    int*      basep  = (int*)alloc((size_t)NBA * NBUCK * 4);
    int*      boff   = (int*)alloc((size_t)(NBUCK + 1) * 4);
    int*      tot    = (int*)alloc((size_t)NBUCK * 4);
    int*      done   = (int*)alloc(256);
    unsigned* ebuf   = (unsigned*)alloc((size_t)E * 4);
    const size_t bfbytes = (size_t)N * DD * 2;
    unsigned short* aggb = (unsigned short*)alloc(bfbytes);   // bf16 agg
    unsigned* Bp     = (unsigned*)alloc((size_t)L * 2 * 16 * 64 * 4 * 4);
    float*    sumsA  = (float*)alloc((size_t)G * DD * 4);    // adjacent with sumsX
    float*    sumsX  = (float*)alloc((size_t)G * DD * 4);
    unsigned short* bfIn = (unsigned short*)alloc(bfbytes);   // cast(x); reused layer-1 out
    unsigned short* bf0  = (unsigned short*)alloc(bfbytes);   // layer-0 out

    // ---- CSR build: all-coalesced counting sort (4 dispatches) ----
    const size_t ldsN = (size_t)NBUCK * 4;
    bucket_count<<<NBA, 256, ldsN, stream>>>(dst, cnt, done, E, NBUCK);
    const int preBlocks = (NBUCK * 64 + 255) / 256;
    bucket_prescan_toff<<<preBlocks, 256, 0, stream>>>(cnt, basep, tot, boff, offs,
                                                       done, NBUCK, E, N);
    bucket_scatter<<<NBA, 256, ldsN, stream>>>(src, dst, basep, boff, ebuf, E, NBUCK);
    bucket_sort<<<NBUCK, 256, 0, stream>>>(ebuf, boff, offs, adj, N);

    // ---- prep: pack W frags + cast x to bf16 (one dispatch) ----
    const long long n8 = (long long)N * DD / 8;
    const int packBlocks = (L * 16 * 64 + 255) / 256;
    prep<<<packBlocks + (int)((n8 + 255) / 256), 256, 0, stream>>>(
        Wl, Wr, Bp, L, x, bfIn, n8, packBlocks);

    // ---- layers 0..L-2: aggregate + MFMA gemm (bf16 ping-pong) ----
    const unsigned short* curb = bfIn;
    unsigned short* bfs[2] = {bf0, bfIn};   // layer 0 -> bf0, layer 1 -> bfIn (dead)
    const int aggB_blocks = (N * 8 + 255) / 256;
    for (int l = 0; l < L - 1; ++l) {
        aggregate_bf16<<<aggB_blocks, 256, 0, stream>>>(curb, aggb, offs, adj, N);
        mfma_gemm<<<1024, 256, 0, stream>>>(aggb, curb, bfs[l & 1],
                                            Bp + (size_t)l * 2 * 16 * 64 * 4,
                                            bl + (size_t)l * DD, N);
        curb = bfs[l & 1];
    }

    // ---- last layer: pooling is linear -> pool(agg), pool(x), tiny GEMM ----
    aggregate_bf16<<<aggB_blocks, 256, 0, stream>>>(curb, aggb, offs, adj, N);
    (void)hipMemsetAsync(sumsA, 0, (size_t)G * DD * 4 * 2, stream);   // sumsA+sumsX adjacent
    pool_partial2<<<2048, 256, 0, stream>>>(aggb, curb, batch, sumsA, sumsX, N);
    final_gemm<<<G, DD, 0, stream>>>(sumsA, sumsX, batch,
                                     Wl + (size_t)(L - 1) * DD * DD,
                                     bl + (size_t)(L - 1) * DD,
                                     Wr + (size_t)(L - 1) * DD * DD,
                                     (float*)d_out, N);
}